// Round 14
// baseline (765.611 us; speedup 1.0000x reference)
//
#include <hip/hip_runtime.h>
#include <hip/hip_bf16.h>

#define NROWS 8192
#define DIM   512
#define KNN   32
#define NPAIR 2048

#define STRIPS 8
#define SCOLS  1024   // columns per strip
#define CHUNK  256    // columns per selection chunk
#define BK     32     // K-step
#define MROWS  128    // rows per WG
#define NSTEP  ((SCOLS / CHUNK) * (DIM / BK))   // 4 * 16 = 64
#define NCAND  (STRIPS * 33)                    // 264

typedef __attribute__((ext_vector_type(8)))  short bf16x8;
typedef __attribute__((ext_vector_type(16))) float f32x16;

__device__ __forceinline__ void gload16(const void* g, void* l) {
    __builtin_amdgcn_global_load_lds(
        (const __attribute__((address_space(1))) void*)g,
        (__attribute__((address_space(3))) void*)l, 16, 0, 0);
}

__device__ __forceinline__ unsigned short bfrne(float x) {
    unsigned u = __float_as_uint(x);
    return (unsigned short)((u + 0x7FFFu + ((u >> 16) & 1u)) >> 16);
}

// ---------------- row squared norms ----------------
__global__ __launch_bounds__(256) void sqnorm_k(const float* __restrict__ E,
                                                float* __restrict__ sq) {
    int row  = blockIdx.x * 4 + (threadIdx.x >> 6);
    int lane = threadIdx.x & 63;
    const float4* e4 = reinterpret_cast<const float4*>(E + (size_t)row * DIM);
    float acc = 0.f;
#pragma unroll
    for (int t = 0; t < 2; ++t) {
        float4 v = e4[lane + 64 * t];
        acc += v.x * v.x + v.y * v.y + v.z * v.z + v.w * v.w;
    }
#pragma unroll
    for (int off = 32; off; off >>= 1) acc += __shfl_xor(acc, off);
    if (lane == 0) sq[row] = acc;
}

// ---------------- split fp32 -> bf16 hi/lo, packed in MFMA-fragment order ----
// Packet p = ((rb32*32 + s)*64 + lane): row = rb32*32 + (lane&31),
// k = s*16 + (lane>>5)*8 + e.  A wave-gload16 of one packet block is a
// contiguous 1KB global read AND the exact LDS fragment layout.
__global__ __launch_bounds__(256) void prep_k(const float* __restrict__ E,
                                              short* __restrict__ Phi,
                                              short* __restrict__ Plo) {
    const int p    = blockIdx.x * 256 + threadIdx.x;
    const int lane = p & 63;
    const int s    = (p >> 6) & 31;
    const int rb   = p >> 11;
    const int row  = rb * 32 + (lane & 31);
    const int k0   = s * 16 + (lane >> 5) * 8;
    const float4* src = reinterpret_cast<const float4*>(E + (size_t)row * DIM + k0);
    float4 x0 = src[0], x1 = src[1];
    float xs[8] = {x0.x, x0.y, x0.z, x0.w, x1.x, x1.y, x1.z, x1.w};
    short hs[8], ls[8];
#pragma unroll
    for (int e = 0; e < 8; ++e) {
        unsigned short hb = bfrne(xs[e]);
        float hf = __uint_as_float(((unsigned)hb) << 16);
        hs[e] = (short)hb;
        ls[e] = (short)bfrne(xs[e] - hf);
    }
    bf16x8 h, l;
#pragma unroll
    for (int e = 0; e < 8; ++e) { h[e] = hs[e]; l[e] = ls[e]; }
    *reinterpret_cast<bf16x8*>(Phi + (size_t)p * 8) = h;
    *reinterpret_cast<bf16x8*>(Plo + (size_t)p * 8) = l;
}

// ---------------- fused distance-GEMM + strip top-33 ----------------
// R13's loop pattern (plain __syncthreads, single-buffered, direct addr)
// with DOUBLED arithmetic intensity: MROWS=128, WG tile 128x256, 8 waves
// (2rg x 4cg), per-wave 64x64 -> 24 MFMA : 16 ds_read per BK=32 step.
// STRIPS=8 keeps grid=512 = 2 WGs/CU. NSTEP=64 (half of R13: barriers
// halve, staged bytes -40%). Selection = R4's verified 16-slot 4-phase.
// SoA emit (R11-verified) + 5-reg merge. LDS 80KB = exactly 2 WGs/CU.
__global__ __launch_bounds__(512, 4) void distsel_k(const short* __restrict__ Phi,
                                                    const short* __restrict__ Plo,
                                                    const float* __restrict__ sq,
                                                    float* __restrict__ cval,
                                                    int* __restrict__ cidx) {
    extern __shared__ char smem[];
    // At: [mat2][rb4][s2][512 shorts]  = 16 KB
    // Bt: [mat2][cb8][s2][512 shorts]  = 32 KB
    // SC: [32][256] f32                = 32 KB   (total 80 KB)
    short* At = (short*)smem;
    short* Bt = (short*)(smem + 16384);
    float* SC = (float*)(smem + 49152);

    const int tid  = threadIdx.x;
    const int w    = tid >> 6;
    const int lane = tid & 63;
    const int kh   = lane >> 5;
    const int c32  = lane & 31;
    const int rg   = w >> 2;          // row-group (0..1): rows rg*64..+63
    const int cg   = w & 3;           // col-group (0..3): cols cg*64..+63
    const int rbk  = blockIdx.x >> 3;
    const int st   = blockIdx.x & 7;
    const int r0   = rbk * MROWS;
    const int cstrip = st * SCOLS;
    const float INF_F = __builtin_inff();

    // stage k-step t: 6 gload16 per wave (2 A slots + 4 B slots)
    auto stage = [&](int t) {
        const int ch = t >> 4, ks = t & 15;
#pragma unroll
        for (int j = 0; j < 2; ++j) {   // A slots a = 2w+j
            const int a = 2 * w + j;
            const int m = a >> 3, rbL = (a >> 1) & 3, s = a & 1;
            const short* Pm = m ? Plo : Phi;
            const size_t pk = ((size_t)(((r0 >> 5) + rbL) * 32 + 2 * ks + s) * 64 + lane) * 8;
            gload16(Pm + pk, At + (((m * 4 + rbL) * 2 + s) * 512));
        }
#pragma unroll
        for (int j = 0; j < 4; ++j) {   // B slots q = 4w+j
            const int q = 4 * w + j;
            const int m = q >> 4, cbL = (q >> 1) & 7, s = q & 1;
            const short* Pm = m ? Plo : Phi;
            const size_t pk = ((size_t)(((cstrip >> 5) + ch * 8 + cbL) * 32 + 2 * ks + s) * 64 + lane) * 8;
            gload16(Pm + pk, Bt + (((m * 8 + cbL) * 2 + s) * 512));
        }
    };

    // selection state: 16 rows per wave (4 quarters x 4 rows), sorted lanes 0..32
    float Tv[16]; int Ti[16];
#pragma unroll
    for (int r = 0; r < 16; ++r) { Tv[r] = INF_F; Ti[r] = -1; }

    f32x16 acc[2][2];
#pragma unroll
    for (int rbs = 0; rbs < 2; ++rbs)
#pragma unroll
        for (int ci = 0; ci < 2; ++ci)
#pragma unroll
            for (int m = 0; m < 16; ++m) acc[rbs][ci][m] = 0.f;

    for (int t = 0; t < NSTEP; ++t) {
        stage(t);
        __syncthreads();   // vmcnt drained -> staged data visible

#pragma unroll
        for (int s = 0; s < 2; ++s) {
            bf16x8 ah[2], al[2], bh[2], bl[2];
#pragma unroll
            for (int rbs = 0; rbs < 2; ++rbs) {
                ah[rbs] = *(const bf16x8*)(At + (((0 * 4 + rg * 2 + rbs) * 2 + s) * 512) + lane * 8);
                al[rbs] = *(const bf16x8*)(At + (((1 * 4 + rg * 2 + rbs) * 2 + s) * 512) + lane * 8);
            }
#pragma unroll
            for (int ci = 0; ci < 2; ++ci) {
                bh[ci] = *(const bf16x8*)(Bt + (((0 * 8 + cg * 2 + ci) * 2 + s) * 512) + lane * 8);
                bl[ci] = *(const bf16x8*)(Bt + (((1 * 8 + cg * 2 + ci) * 2 + s) * 512) + lane * 8);
            }
#pragma unroll
            for (int rbs = 0; rbs < 2; ++rbs)
#pragma unroll
                for (int ci = 0; ci < 2; ++ci) {
                    acc[rbs][ci] = __builtin_amdgcn_mfma_f32_32x32x16_bf16(ah[rbs], bh[ci], acc[rbs][ci], 0, 0, 0);
                    acc[rbs][ci] = __builtin_amdgcn_mfma_f32_32x32x16_bf16(ah[rbs], bl[ci], acc[rbs][ci], 0, 0, 0);
                    acc[rbs][ci] = __builtin_amdgcn_mfma_f32_32x32x16_bf16(al[rbs], bh[ci], acc[rbs][ci], 0, 0, 0);
                }
        }

        if ((t & 15) != 15) {
            __syncthreads();   // compute done -> buffers free for next stage
        } else {
            // -------- chunk done: R4's verified 4-phase select (32 rows/phase)
            const int ch = t >> 4;
            const int c0 = cstrip + ch * CHUNK;
            const float sqv0 = sq[c0 + cg * 64 + c32];
            const float sqv1 = sq[c0 + cg * 64 + 32 + c32];
#pragma unroll
            for (int q = 0; q < 4; ++q) {
                if (rg == (q >> 1)) {
                    const int ri = q & 1;
#pragma unroll
                    for (int ci = 0; ci < 2; ++ci) {
                        const float sv = ci ? sqv1 : sqv0;
#pragma unroll
                        for (int m = 0; m < 16; ++m) {
                            const int sub = (m & 3) + 8 * (m >> 2) + 4 * kh;
                            SC[sub * CHUNK + cg * 64 + ci * 32 + c32] = sv - 2.f * acc[ri][ci][m];
                        }
                    }
                }
                __syncthreads();
#pragma unroll
                for (int rr = 0; rr < 4; ++rr) {
                    float& tv = Tv[q * 4 + rr];
                    int&   ti = Ti[q * 4 + rr];
                    const float4 f = *(const float4*)(SC + (4 * w + rr) * CHUNK + 4 * lane);
                    float mn = fminf(fminf(f.x, f.y), fminf(f.z, f.w));
                    float t0e = INF_F;
                    if (ch == 0) {
                        // bitonic-sort the 64 per-lane mins; 33rd smallest is a
                        // valid upper bound on the chunk's true 33rd smallest.
                        float v = mn;
#pragma unroll
                        for (int k = 2; k <= 64; k <<= 1)
#pragma unroll
                            for (int j = k >> 1; j; j >>= 1) {
                                float o = __shfl_xor(v, j);
                                const bool lower = ((lane & j) == 0);
                                const bool dir   = ((lane & k) == 0);
                                v = (lower == dir) ? fminf(v, o) : fmaxf(v, o);
                            }
                        float t0 = __shfl(v, 32);
                        t0e = t0 + fabsf(t0) * 1e-6f + 1e-30f;   // nudge up
                    }
                    float lthr = __shfl(tv, 32);
                    float gate = fminf(lthr, t0e);
                    while (true) {
                        unsigned long long bal = __ballot(mn < gate);
                        if (!bal) break;
                        const int src = (int)__builtin_ctzll(bal);
                        const float gx = __shfl(f.x, src);
                        const float gy = __shfl(f.y, src);
                        const float gz = __shfl(f.z, src);
                        const float gw = __shfl(f.w, src);
                        const int jc0 = c0 + 4 * src;
                        if (lane == src) mn = INF_F;
#define INS(VV, JJ)                                                         \
                        if ((VV) < gate) {                                  \
                            float pv = __shfl_up(tv, 1);                    \
                            int   pi = __shfl_up(ti, 1);                    \
                            if (lane == 0) pv = -INF_F;                     \
                            if (tv > (VV)) {                                \
                                const bool tk = pv > (VV);                  \
                                tv = tk ? pv : (VV);                        \
                                ti = tk ? pi : (JJ);                        \
                            }                                               \
                            lthr = __shfl(tv, 32);                          \
                            gate = fminf(lthr, t0e);                        \
                        }
                        INS(gx, jc0); INS(gy, jc0 + 1); INS(gz, jc0 + 2); INS(gw, jc0 + 3);
#undef INS
                    }
                }
                __syncthreads();
            }
            // reset accumulators for next chunk
#pragma unroll
            for (int rbs = 0; rbs < 2; ++rbs)
#pragma unroll
                for (int ci = 0; ci < 2; ++ci)
#pragma unroll
                    for (int m = 0; m < 16; ++m) acc[rbs][ci][m] = 0.f;
        }
    }

    // SoA emit: cval[st][row][33] — strip plane written only by its own WGs
#pragma unroll
    for (int q = 0; q < 4; ++q)
#pragma unroll
        for (int rr = 0; rr < 4; ++rr) {
            const int grow = r0 + 32 * q + 4 * w + rr;
            if (lane <= 32) {
                cval[(size_t)st * (NROWS * 33) + (size_t)grow * 33 + lane] = Tv[q * 4 + rr];
                cidx[(size_t)st * (NROWS * 33) + (size_t)grow * 33 + lane] = Ti[q * 4 + rr];
            }
        }
}

// ---------------- merge strips: global top-33 of 264 (SoA), drop self -------
__global__ __launch_bounds__(256) void merge_k(const float* __restrict__ cval,
                                               const int* __restrict__ cidx,
                                               int* __restrict__ knn) {
    const int row  = blockIdx.x * 4 + (threadIdx.x >> 6);
    const int lane = threadIdx.x & 63;
    const float INF_F = __builtin_inff();
    float vv[5]; int ii[5];
#pragma unroll
    for (int k = 0; k < 5; ++k) {
        const int idx = lane + 64 * k;
        const bool ok = idx < NCAND;
        const int stt = idx / 33;
        const int e   = idx - 33 * stt;
        const size_t off = (size_t)stt * (NROWS * 33) + (size_t)row * 33 + e;
        vv[k] = ok ? cval[off] : INF_F;
        ii[k] = ok ? cidx[off] : 0x7FFFFFFF;
    }
    for (int it = 0; it < 33; ++it) {
        float mv = vv[0]; int mi = ii[0]; int ms = 0;
#pragma unroll
        for (int k = 1; k < 5; ++k)
            if (vv[k] < mv || (vv[k] == mv && ii[k] < mi)) { mv = vv[k]; mi = ii[k]; ms = k; }
        float bv = mv; int bi = mi; int bl = lane;
#pragma unroll
        for (int off = 32; off; off >>= 1) {
            float ov = __shfl_xor(bv, off);
            int   oi = __shfl_xor(bi, off);
            int   ol = __shfl_xor(bl, off);
            if (ov < bv || (ov == bv && oi < bi)) { bv = ov; bi = oi; bl = ol; }
        }
        if (it > 0 && lane == 0) knn[(size_t)row * KNN + it - 1] = bi;
        if (lane == bl) {
#pragma unroll
            for (int k = 0; k < 5; ++k)
                if (k == ms) vv[k] = INF_F;
        }
    }
}

// ---------------- overlap + rank + per-pair partial loss ----------------
__global__ __launch_bounds__(64) void overlap_k(const int* __restrict__ knn,
                                                const int* __restrict__ pairs,
                                                const float* __restrict__ refso,
                                                float* __restrict__ partial) {
    const int p    = blockIdx.x;
    const int lane = threadIdx.x;
    __shared__ int si[KNN];
    const int i = pairs[p];
    if (lane < KNN) si[lane] = knn[(size_t)i * KNN + lane];
    __syncthreads();

    float v = 0.f;
    if (lane < KNN) {
        const int j = si[lane];
        int t[KNN];
        const int4* kj = reinterpret_cast<const int4*>(knn + (size_t)j * KNN);
#pragma unroll
        for (int b = 0; b < KNN / 4; ++b) {
            int4 q = kj[b];
            t[4 * b + 0] = q.x; t[4 * b + 1] = q.y;
            t[4 * b + 2] = q.z; t[4 * b + 3] = q.w;
        }
        int cnt = 0;
        for (int a = 0; a < KNN; ++a) {
            int sa = si[a];
#pragma unroll
            for (int b = 0; b < KNN; ++b) cnt += (t[b] == sa);
        }
        v = (float)cnt * (1.0f / KNN);
    }
    int rank = 0;
    for (int q = 0; q < KNN; ++q) {
        float ov = __shfl(v, q);
        rank += (lane < KNN) && ((ov < v) || (ov == v && q < lane));
    }
    float err = 0.f;
    if (lane < KNN) {
        float r = refso[(size_t)p * KNN + rank];
        float d = v - r;
        err = d * d;
    }
#pragma unroll
    for (int off = 32; off; off >>= 1) err += __shfl_xor(err, off);
    if (lane == 0) partial[p] = err;
}

// ---------------- deterministic final reduce ----------------
__global__ __launch_bounds__(256) void final_k(const float* __restrict__ partial,
                                               float* __restrict__ out) {
    const int tid = threadIdx.x;
    float a = 0.f;
    for (int q = tid; q < NPAIR; q += 256) a += partial[q];
#pragma unroll
    for (int off = 32; off; off >>= 1) a += __shfl_xor(a, off);
    __shared__ float red[4];
    if ((tid & 63) == 0) red[tid >> 6] = a;
    __syncthreads();
    if (tid == 0)
        out[0] = (red[0] + red[1] + red[2] + red[3]) * (1.0f / (NPAIR * KNN));
}

// ================= round-1 fallback (used only if ws too small) =================
__global__ __launch_bounds__(256) void dist_topk_k(const float* __restrict__ E,
                                                   const float* __restrict__ sq,
                                                   int* __restrict__ knn) {
    extern __shared__ float sc[];
    const int tid = threadIdx.x;
    const int r0  = blockIdx.x * 4;
    const float4* a0 = reinterpret_cast<const float4*>(E + (size_t)(r0 + 0) * DIM);
    const float4* a1 = reinterpret_cast<const float4*>(E + (size_t)(r0 + 1) * DIM);
    const float4* a2 = reinterpret_cast<const float4*>(E + (size_t)(r0 + 2) * DIM);
    const float4* a3 = reinterpret_cast<const float4*>(E + (size_t)(r0 + 3) * DIM);
    for (int tile = 0; tile < NROWS / 256; ++tile) {
        int j = tile * 256 + tid;
        const float4* bj = reinterpret_cast<const float4*>(E + (size_t)j * DIM);
        float acc0 = 0.f, acc1 = 0.f, acc2 = 0.f, acc3 = 0.f;
#pragma unroll 4
        for (int dd = 0; dd < DIM / 4; ++dd) {
            float4 b  = bj[dd];
            float4 x0 = a0[dd], x1 = a1[dd], x2 = a2[dd], x3 = a3[dd];
            acc0 += x0.x * b.x + x0.y * b.y + x0.z * b.z + x0.w * b.w;
            acc1 += x1.x * b.x + x1.y * b.y + x1.z * b.z + x1.w * b.w;
            acc2 += x2.x * b.x + x2.y * b.y + x2.z * b.z + x2.w * b.w;
            acc3 += x3.x * b.x + x3.y * b.y + x3.z * b.z + x3.w * b.w;
        }
        float sj = sq[j];
        sc[0 * NROWS + j] = sj - 2.f * acc0;
        sc[1 * NROWS + j] = sj - 2.f * acc1;
        sc[2 * NROWS + j] = sj - 2.f * acc2;
        sc[3 * NROWS + j] = sj - 2.f * acc3;
    }
    __syncthreads();
    const int w    = tid >> 6;
    const int lane = tid & 63;
    float* s = sc + w * NROWS;
    const float INF = __builtin_inff();
    float m[4]; int mi[4];
#pragma unroll
    for (int b = 0; b < 4; ++b) {
        float bm = INF; int bmi = NROWS;
        for (int t = 0; t < 32; ++t) {
            int j = lane + 64 * (b * 32 + t);
            float v = s[j];
            if (v < bm || (v == bm && j < bmi)) { bm = v; bmi = j; }
        }
        m[b] = bm; mi[b] = bmi;
    }
    const int row = r0 + w;
    for (int it = 0; it < KNN + 1; ++it) {
        float cvv = m[0]; int cii = mi[0];
#pragma unroll
        for (int b = 1; b < 4; ++b)
            if (m[b] < cvv || (m[b] == cvv && mi[b] < cii)) { cvv = m[b]; cii = mi[b]; }
        float bv = cvv; int bi = cii;
#pragma unroll
        for (int off = 32; off; off >>= 1) {
            float ov = __shfl_xor(bv, off);
            int   oi = __shfl_xor(bi, off);
            if (ov < bv || (ov == bv && oi < bi)) { bv = ov; bi = oi; }
        }
        if (it > 0 && lane == 0) knn[(size_t)row * KNN + (it - 1)] = bi;
        int ol = bi & 63;
        if (lane == ol) {
            s[bi] = INF;
            int b = (bi >> 6) >> 5;
            float bm = INF; int bmi = NROWS;
            for (int t = 0; t < 32; ++t) {
                int j = lane + 64 * (b * 32 + t);
                float v = s[j];
                if (v < bm || (v == bm && j < bmi)) { bm = v; bmi = j; }
            }
            m[b] = bm; mi[b] = bmi;
        }
    }
}

extern "C" void kernel_launch(void* const* d_in, const int* in_sizes, int n_in,
                              void* d_out, int out_size, void* d_ws, size_t ws_size,
                              hipStream_t stream) {
    const float* E     = (const float*)d_in[0];
    const float* refso = (const float*)d_in[1];
    const int*   pairs = (const int*)d_in[2];
    float* out = (float*)d_out;

    char* ws = (char*)d_ws;
    float* sq      = (float*)ws;                         // 32 KB
    float* partial = (float*)(ws + 32768);               // 8 KB
    int*   knn     = (int*)(ws + 40960);                 // 1 MB
    short* Phi     = (short*)(ws + 1089536);             // 8 MB packed hi
    short* Plo     = (short*)(ws + 9478144);             // 8 MB packed lo
    float* cval    = (float*)(ws + 17866752);            // 8*8192*33*4 = 8.65 MB
    int*   cidx    = (int*)(ws + 26517504);              // 8.65 MB
    const size_t NEED = 35168256;

    if (ws_size >= NEED) {
        hipFuncSetAttribute((const void*)distsel_k,
                            hipFuncAttributeMaxDynamicSharedMemorySize, 81920);
        sqnorm_k<<<NROWS / 4, 256, 0, stream>>>(E, sq);
        prep_k<<<NROWS * DIM / 8 / 256, 256, 0, stream>>>(E, Phi, Plo);
        distsel_k<<<(NROWS / MROWS) * STRIPS, 512, 81920, stream>>>(Phi, Plo, sq, cval, cidx);
        merge_k<<<NROWS / 4, 256, 0, stream>>>(cval, cidx, knn);
    } else {
        hipFuncSetAttribute((const void*)dist_topk_k,
                            hipFuncAttributeMaxDynamicSharedMemorySize, 131072);
        sqnorm_k<<<NROWS / 4, 256, 0, stream>>>(E, sq);
        dist_topk_k<<<NROWS / 4, 256, 131072, stream>>>(E, sq, knn);
    }
    overlap_k<<<NPAIR, 64, 0, stream>>>(knn, pairs, refso, partial);
    final_k<<<1, 256, 0, stream>>>(partial, out);
}

// Round 15
// 570.930 us; speedup vs baseline: 1.3410x; 1.3410x over previous
//
#include <hip/hip_runtime.h>
#include <hip/hip_bf16.h>

#define NROWS 8192
#define DIM   512
#define KNN   32
#define NPAIR 2048

#define STRIPS 4
#define SCOLS  2048   // columns per strip
#define CHUNK  256    // columns per chunk
#define BK     32     // K-step
#define MROWS  64     // rows per WG
#define NSTEP  ((SCOLS / CHUNK) * (DIM / BK))   // 8 * 16 = 128

typedef __attribute__((ext_vector_type(8)))  short bf16x8;
typedef __attribute__((ext_vector_type(16))) float f32x16;

__device__ __forceinline__ void gload16(const void* g, void* l) {
    __builtin_amdgcn_global_load_lds(
        (const __attribute__((address_space(1))) void*)g,
        (__attribute__((address_space(3))) void*)l, 16, 0, 0);
}

__device__ __forceinline__ unsigned short bfrne(float x) {
    unsigned u = __float_as_uint(x);
    return (unsigned short)((u + 0x7FFFu + ((u >> 16) & 1u)) >> 16);
}

// ---------------- row squared norms ----------------
__global__ __launch_bounds__(256) void sqnorm_k(const float* __restrict__ E,
                                                float* __restrict__ sq) {
    int row  = blockIdx.x * 4 + (threadIdx.x >> 6);
    int lane = threadIdx.x & 63;
    const float4* e4 = reinterpret_cast<const float4*>(E + (size_t)row * DIM);
    float acc = 0.f;
#pragma unroll
    for (int t = 0; t < 2; ++t) {
        float4 v = e4[lane + 64 * t];
        acc += v.x * v.x + v.y * v.y + v.z * v.z + v.w * v.w;
    }
#pragma unroll
    for (int off = 32; off; off >>= 1) acc += __shfl_xor(acc, off);
    if (lane == 0) sq[row] = acc;
}

// ---------------- split fp32 -> bf16 hi/lo, packed in MFMA-fragment order ----
// Packet p = ((rb32*32 + s)*64 + lane): row = rb32*32 + (lane&31),
// k = s*16 + (lane>>5)*8 + e.  A wave-gload16 of one packet block is a
// contiguous 1KB global read AND the exact LDS fragment layout.
__global__ __launch_bounds__(256) void prep_k(const float* __restrict__ E,
                                              short* __restrict__ Phi,
                                              short* __restrict__ Plo) {
    const int p    = blockIdx.x * 256 + threadIdx.x;
    const int lane = p & 63;
    const int s    = (p >> 6) & 31;
    const int rb   = p >> 11;
    const int row  = rb * 32 + (lane & 31);
    const int k0   = s * 16 + (lane >> 5) * 8;
    const float4* src = reinterpret_cast<const float4*>(E + (size_t)row * DIM + k0);
    float4 x0 = src[0], x1 = src[1];
    float xs[8] = {x0.x, x0.y, x0.z, x0.w, x1.x, x1.y, x1.z, x1.w};
    short hs[8], ls[8];
#pragma unroll
    for (int e = 0; e < 8; ++e) {
        unsigned short hb = bfrne(xs[e]);
        float hf = __uint_as_float(((unsigned)hb) << 16);
        hs[e] = (short)hb;
        ls[e] = (short)bfrne(xs[e] - hf);
    }
    bf16x8 h, l;
#pragma unroll
    for (int e = 0; e < 8; ++e) { h[e] = hs[e]; l[e] = ls[e]; }
    *reinterpret_cast<bf16x8*>(Phi + (size_t)p * 8) = h;
    *reinterpret_cast<bf16x8*>(Plo + (size_t)p * 8) = l;
}

// ---------------- fused distance-GEMM + strip top-33 (session champion) -----
// 512 threads (8 waves). WG tile 64x256, per-wave 32x64 (acc[2] of 32x32).
// Grid 512 = 2 WGs/CU: cross-WG overlap fills staging/barrier/selection
// stalls. Single-buffered stage -> __syncthreads -> compute. Incremental
// staging pointers. Empirical optimum of this design family: dbuf, counted
// vmcnt rings, decoupled GEMM+select, strip/emit reshapes all regressed
// (rounds 4-14); LDS-read floor ~123us + L3 staging latency under the
// per-step drain barrier is the binding constraint at HIP source level.
__global__ __launch_bounds__(512, 4) void distsel_k(const short* __restrict__ Phi,
                                                    const short* __restrict__ Plo,
                                                    const float* __restrict__ sq,
                                                    float* __restrict__ cval,
                                                    int* __restrict__ cidx) {
    extern __shared__ char smem[];
    // At: [mat2][rb2][s2][512 shorts]  =  8 KB
    // Bt: [mat2][cb8][s2][512 shorts]  = 32 KB
    // SC: [32][256] f32                = 32 KB
    short* At = (short*)smem;
    short* Bt = (short*)(smem + 8192);
    float* SC = (float*)(smem + 40960);

    const int tid  = threadIdx.x;
    const int w    = tid >> 6;
    const int lane = tid & 63;
    const int kh   = lane >> 5;
    const int c32  = lane & 31;
    const int rbk  = blockIdx.x >> 2;
    const int st   = blockIdx.x & 3;
    const int r0   = rbk * MROWS;
    const int cstrip = st * SCOLS;
    const float INF_F = __builtin_inff();

    const int rb  = w >> 2;          // wave's rowblock (0..1)
    const int cb0 = 2 * (w & 3);     // wave's first colblock (0,2,4,6)

    // ---- incremental staging pointers ----
    const int mat = w >> 2;          // waves 0-3 stage hi, 4-7 lo
    const short* __restrict__ Pm = mat ? Plo : Phi;
    const int rbL = (w >> 1) & 1, sA = w & 1;
    const short* pA = Pm + ((size_t)(((r0 >> 5) + rbL) * 32 + sA)) * 512 + lane * 8;
    short* const dA = At + (((mat * 2 + rbL) * 2 + sA) * 512);
    const short* pB[4];
    short* dB[4];
#pragma unroll
    for (int j = 0; j < 4; ++j) {
        const int cbL = (2 * w + (j >> 1)) & 7, sB = j & 1;
        pB[j] = Pm + ((size_t)(((cstrip >> 5) + cbL) * 32 + sB)) * 512 + lane * 8;
        dB[j] = Bt + (((mat * 8 + cbL) * 2 + sB) * 512);
    }

    // selection state: 8 rows per wave (2 phases x 4 rows), sorted lanes 0..32
    float Tv[8]; int Ti[8];
#pragma unroll
    for (int r = 0; r < 8; ++r) { Tv[r] = INF_F; Ti[r] = -1; }

    f32x16 acc[2];
#pragma unroll
    for (int ci = 0; ci < 2; ++ci)
#pragma unroll
        for (int m = 0; m < 16; ++m) acc[ci][m] = 0.f;

    for (int t = 0; t < NSTEP; ++t) {
        // stage step t (pointers already positioned)
        gload16(pA, dA);
#pragma unroll
        for (int j = 0; j < 4; ++j) gload16(pB[j], dB[j]);
        // advance pointers for step t+1
        if ((t & 15) == 15) {
            pA -= 15360;                       // back to ksg=0 (A repeats per chunk)
#pragma unroll
            for (int j = 0; j < 4; ++j) pB[j] += 115712;   // next chunk base
        } else {
            pA += 1024;
#pragma unroll
            for (int j = 0; j < 4; ++j) pB[j] += 1024;
        }
        __syncthreads();   // vmcnt drained -> staged data visible

#pragma unroll
        for (int s = 0; s < 2; ++s) {
            const bf16x8 ah = *(const bf16x8*)(At + (((0 * 2 + rb) * 2 + s) * 512) + lane * 8);
            const bf16x8 al = *(const bf16x8*)(At + (((1 * 2 + rb) * 2 + s) * 512) + lane * 8);
#pragma unroll
            for (int ci = 0; ci < 2; ++ci) {
                const bf16x8 bh = *(const bf16x8*)(Bt + (((0 * 8 + cb0 + ci) * 2 + s) * 512) + lane * 8);
                const bf16x8 bl = *(const bf16x8*)(Bt + (((1 * 8 + cb0 + ci) * 2 + s) * 512) + lane * 8);
                acc[ci] = __builtin_amdgcn_mfma_f32_32x32x16_bf16(ah, bh, acc[ci], 0, 0, 0);
                acc[ci] = __builtin_amdgcn_mfma_f32_32x32x16_bf16(ah, bl, acc[ci], 0, 0, 0);
                acc[ci] = __builtin_amdgcn_mfma_f32_32x32x16_bf16(al, bh, acc[ci], 0, 0, 0);
            }
        }

        if ((t & 15) != 15) {
            __syncthreads();   // compute done -> buffers free for next stage
        } else {
            // -------- chunk done: scores -> SC (two 32-row phases) -> selection
            const int ch = t >> 4;
            const int c0 = cstrip + ch * CHUNK;
            const float sqv0 = sq[c0 + (cb0 + 0) * 32 + c32];
            const float sqv1 = sq[c0 + (cb0 + 1) * 32 + c32];
#pragma unroll
            for (int ph = 0; ph < 2; ++ph) {
                if (rb == ph) {
#pragma unroll
                    for (int ci = 0; ci < 2; ++ci) {
                        const float sv = ci ? sqv1 : sqv0;
#pragma unroll
                        for (int m = 0; m < 16; ++m) {
                            const int sub = (m & 3) + 8 * (m >> 2) + 4 * kh;
                            SC[sub * CHUNK + (cb0 + ci) * 32 + c32] = sv - 2.f * acc[ci][m];
                        }
                    }
                }
                __syncthreads();
#pragma unroll
                for (int rr = 0; rr < 4; ++rr) {
                    float& tv = Tv[ph * 4 + rr];
                    int&   ti = Ti[ph * 4 + rr];
                    const float4 f = *(const float4*)(SC + (4 * w + rr) * CHUNK + 4 * lane);
                    float mn = fminf(fminf(f.x, f.y), fminf(f.z, f.w));
                    float t0e = INF_F;
                    if (ch == 0) {
                        // bitonic-sort the 64 per-lane mins; 33rd smallest is a
                        // valid upper bound on the chunk's true 33rd smallest.
                        float v = mn;
#pragma unroll
                        for (int k = 2; k <= 64; k <<= 1)
#pragma unroll
                            for (int j = k >> 1; j; j >>= 1) {
                                float o = __shfl_xor(v, j);
                                const bool lower = ((lane & j) == 0);
                                const bool dir   = ((lane & k) == 0);
                                v = (lower == dir) ? fminf(v, o) : fmaxf(v, o);
                            }
                        float t0 = __shfl(v, 32);
                        t0e = t0 + fabsf(t0) * 1e-6f + 1e-30f;   // nudge up
                    }
                    float lthr = __shfl(tv, 32);
                    float gate = fminf(lthr, t0e);
                    while (true) {
                        unsigned long long bal = __ballot(mn < gate);
                        if (!bal) break;
                        const int src = (int)__builtin_ctzll(bal);
                        const float gx = __shfl(f.x, src);
                        const float gy = __shfl(f.y, src);
                        const float gz = __shfl(f.z, src);
                        const float gw = __shfl(f.w, src);
                        const int jc0 = c0 + 4 * src;
                        if (lane == src) mn = INF_F;
#define INS(VV, JJ)                                                         \
                        if ((VV) < gate) {                                  \
                            float pv = __shfl_up(tv, 1);                    \
                            int   pi = __shfl_up(ti, 1);                    \
                            if (lane == 0) pv = -INF_F;                     \
                            if (tv > (VV)) {                                \
                                const bool tk = pv > (VV);                  \
                                tv = tk ? pv : (VV);                        \
                                ti = tk ? pi : (JJ);                        \
                            }                                               \
                            lthr = __shfl(tv, 32);                          \
                            gate = fminf(lthr, t0e);                        \
                        }
                        INS(gx, jc0); INS(gy, jc0 + 1); INS(gz, jc0 + 2); INS(gw, jc0 + 3);
#undef INS
                    }
                }
                __syncthreads();
            }
            // reset accumulators for next chunk
#pragma unroll
            for (int ci = 0; ci < 2; ++ci)
#pragma unroll
                for (int m = 0; m < 16; ++m) acc[ci][m] = 0.f;
        }
    }

    // emit 33 sorted candidates per row for this strip (AoS: coalesces cleanly)
#pragma unroll
    for (int ph = 0; ph < 2; ++ph)
#pragma unroll
        for (int rr = 0; rr < 4; ++rr) {
            const int grow = r0 + 32 * ph + 4 * w + rr;
            if (lane <= 32) {
                cval[(size_t)grow * (STRIPS * 33) + st * 33 + lane] = Tv[ph * 4 + rr];
                cidx[(size_t)grow * (STRIPS * 33) + st * 33 + lane] = Ti[ph * 4 + rr];
            }
        }
}

// ---------------- merge strips: global top-33, drop self (rank 0) ----------------
__global__ __launch_bounds__(256) void merge_k(const float* __restrict__ cval,
                                               const int* __restrict__ cidx,
                                               int* __restrict__ knn) {
    const int row  = blockIdx.x * 4 + (threadIdx.x >> 6);
    const int lane = threadIdx.x & 63;
    const float INF_F = __builtin_inff();
    const float* cv = cval + (size_t)row * (STRIPS * 33);
    const int*   ci = cidx + (size_t)row * (STRIPS * 33);
    float v0 = cv[lane];       int i0 = ci[lane];
    float v1 = cv[lane + 64];  int i1 = ci[lane + 64];
    float v2 = (lane + 128 < STRIPS * 33) ? cv[lane + 128] : INF_F;
    int   i2 = (lane + 128 < STRIPS * 33) ? ci[lane + 128] : 0x7FFFFFFF;
    for (int it = 0; it < 33; ++it) {
        float mv = v0; int mi = i0; int ms = 0;
        if (v1 < mv || (v1 == mv && i1 < mi)) { mv = v1; mi = i1; ms = 1; }
        if (v2 < mv || (v2 == mv && i2 < mi)) { mv = v2; mi = i2; ms = 2; }
        float bv = mv; int bi = mi; int bl = lane;
#pragma unroll
        for (int off = 32; off; off >>= 1) {
            float ov = __shfl_xor(bv, off);
            int   oi = __shfl_xor(bi, off);
            int   ol = __shfl_xor(bl, off);
            if (ov < bv || (ov == bv && oi < bi)) { bv = ov; bi = oi; bl = ol; }
        }
        if (it > 0 && lane == 0) knn[(size_t)row * KNN + it - 1] = bi;
        if (lane == bl) {
            if (ms == 0) v0 = INF_F; else if (ms == 1) v1 = INF_F; else v2 = INF_F;
        }
    }
}

// ---------------- overlap + rank + per-pair partial loss ----------------
__global__ __launch_bounds__(64) void overlap_k(const int* __restrict__ knn,
                                                const int* __restrict__ pairs,
                                                const float* __restrict__ refso,
                                                float* __restrict__ partial) {
    const int p    = blockIdx.x;
    const int lane = threadIdx.x;
    __shared__ int si[KNN];
    const int i = pairs[p];
    if (lane < KNN) si[lane] = knn[(size_t)i * KNN + lane];
    __syncthreads();

    float v = 0.f;
    if (lane < KNN) {
        const int j = si[lane];
        int t[KNN];
        const int4* kj = reinterpret_cast<const int4*>(knn + (size_t)j * KNN);
#pragma unroll
        for (int b = 0; b < KNN / 4; ++b) {
            int4 q = kj[b];
            t[4 * b + 0] = q.x; t[4 * b + 1] = q.y;
            t[4 * b + 2] = q.z; t[4 * b + 3] = q.w;
        }
        int cnt = 0;
        for (int a = 0; a < KNN; ++a) {
            int sa = si[a];
#pragma unroll
            for (int b = 0; b < KNN; ++b) cnt += (t[b] == sa);
        }
        v = (float)cnt * (1.0f / KNN);
    }
    int rank = 0;
    for (int q = 0; q < KNN; ++q) {
        float ov = __shfl(v, q);
        rank += (lane < KNN) && ((ov < v) || (ov == v && q < lane));
    }
    float err = 0.f;
    if (lane < KNN) {
        float r = refso[(size_t)p * KNN + rank];
        float d = v - r;
        err = d * d;
    }
#pragma unroll
    for (int off = 32; off; off >>= 1) err += __shfl_xor(err, off);
    if (lane == 0) partial[p] = err;
}

// ---------------- deterministic final reduce ----------------
__global__ __launch_bounds__(256) void final_k(const float* __restrict__ partial,
                                               float* __restrict__ out) {
    const int tid = threadIdx.x;
    float a = 0.f;
    for (int q = tid; q < NPAIR; q += 256) a += partial[q];
#pragma unroll
    for (int off = 32; off; off >>= 1) a += __shfl_xor(a, off);
    __shared__ float red[4];
    if ((tid & 63) == 0) red[tid >> 6] = a;
    __syncthreads();
    if (tid == 0)
        out[0] = (red[0] + red[1] + red[2] + red[3]) * (1.0f / (NPAIR * KNN));
}

// ================= round-1 fallback (used only if ws too small) =================
__global__ __launch_bounds__(256) void dist_topk_k(const float* __restrict__ E,
                                                   const float* __restrict__ sq,
                                                   int* __restrict__ knn) {
    extern __shared__ float sc[];
    const int tid = threadIdx.x;
    const int r0  = blockIdx.x * 4;
    const float4* a0 = reinterpret_cast<const float4*>(E + (size_t)(r0 + 0) * DIM);
    const float4* a1 = reinterpret_cast<const float4*>(E + (size_t)(r0 + 1) * DIM);
    const float4* a2 = reinterpret_cast<const float4*>(E + (size_t)(r0 + 2) * DIM);
    const float4* a3 = reinterpret_cast<const float4*>(E + (size_t)(r0 + 3) * DIM);
    for (int tile = 0; tile < NROWS / 256; ++tile) {
        int j = tile * 256 + tid;
        const float4* bj = reinterpret_cast<const float4*>(E + (size_t)j * DIM);
        float acc0 = 0.f, acc1 = 0.f, acc2 = 0.f, acc3 = 0.f;
#pragma unroll 4
        for (int dd = 0; dd < DIM / 4; ++dd) {
            float4 b  = bj[dd];
            float4 x0 = a0[dd], x1 = a1[dd], x2 = a2[dd], x3 = a3[dd];
            acc0 += x0.x * b.x + x0.y * b.y + x0.z * b.z + x0.w * b.w;
            acc1 += x1.x * b.x + x1.y * b.y + x1.z * b.z + x1.w * b.w;
            acc2 += x2.x * b.x + x2.y * b.y + x2.z * b.z + x2.w * b.w;
            acc3 += x3.x * b.x + x3.y * b.y + x3.z * b.z + x3.w * b.w;
        }
        float sj = sq[j];
        sc[0 * NROWS + j] = sj - 2.f * acc0;
        sc[1 * NROWS + j] = sj - 2.f * acc1;
        sc[2 * NROWS + j] = sj - 2.f * acc2;
        sc[3 * NROWS + j] = sj - 2.f * acc3;
    }
    __syncthreads();
    const int w    = tid >> 6;
    const int lane = tid & 63;
    float* s = sc + w * NROWS;
    const float INF = __builtin_inff();
    float m[4]; int mi[4];
#pragma unroll
    for (int b = 0; b < 4; ++b) {
        float bm = INF; int bmi = NROWS;
        for (int t = 0; t < 32; ++t) {
            int j = lane + 64 * (b * 32 + t);
            float v = s[j];
            if (v < bm || (v == bm && j < bmi)) { bm = v; bmi = j; }
        }
        m[b] = bm; mi[b] = bmi;
    }
    const int row = r0 + w;
    for (int it = 0; it < KNN + 1; ++it) {
        float cvv = m[0]; int cii = mi[0];
#pragma unroll
        for (int b = 1; b < 4; ++b)
            if (m[b] < cvv || (m[b] == cvv && mi[b] < cii)) { cvv = m[b]; cii = mi[b]; }
        float bv = cvv; int bi = cii;
#pragma unroll
        for (int off = 32; off; off >>= 1) {
            float ov = __shfl_xor(bv, off);
            int   oi = __shfl_xor(bi, off);
            if (ov < bv || (ov == bv && oi < bi)) { bv = ov; bi = oi; }
        }
        if (it > 0 && lane == 0) knn[(size_t)row * KNN + (it - 1)] = bi;
        int ol = bi & 63;
        if (lane == ol) {
            s[bi] = INF;
            int b = (bi >> 6) >> 5;
            float bm = INF; int bmi = NROWS;
            for (int t = 0; t < 32; ++t) {
                int j = lane + 64 * (b * 32 + t);
                float v = s[j];
                if (v < bm || (v == bm && j < bmi)) { bm = v; bmi = j; }
            }
            m[b] = bm; mi[b] = bmi;
        }
    }
}

extern "C" void kernel_launch(void* const* d_in, const int* in_sizes, int n_in,
                              void* d_out, int out_size, void* d_ws, size_t ws_size,
                              hipStream_t stream) {
    const float* E     = (const float*)d_in[0];
    const float* refso = (const float*)d_in[1];
    const int*   pairs = (const int*)d_in[2];
    float* out = (float*)d_out;

    char* ws = (char*)d_ws;
    float* sq      = (float*)ws;                         // 32 KB
    float* partial = (float*)(ws + 32768);               // 8 KB
    int*   knn     = (int*)(ws + 40960);                 // 1 MB
    short* Phi     = (short*)(ws + 1089536);             // 8 MB packed hi
    short* Plo     = (short*)(ws + 9478144);             // 8 MB packed lo
    float* cval    = (float*)(ws + 17866752);            // 4.125 MB
    int*   cidx    = (int*)(ws + 22192128);              // 4.125 MB
    const size_t NEED = 26517504;

    if (ws_size >= NEED) {
        hipFuncSetAttribute((const void*)distsel_k,
                            hipFuncAttributeMaxDynamicSharedMemorySize, 73728);
        sqnorm_k<<<NROWS / 4, 256, 0, stream>>>(E, sq);
        prep_k<<<NROWS * DIM / 8 / 256, 256, 0, stream>>>(E, Phi, Plo);
        distsel_k<<<(NROWS / MROWS) * STRIPS, 512, 73728, stream>>>(Phi, Plo, sq, cval, cidx);
        merge_k<<<NROWS / 4, 256, 0, stream>>>(cval, cidx, knn);
    } else {
        hipFuncSetAttribute((const void*)dist_topk_k,
                            hipFuncAttributeMaxDynamicSharedMemorySize, 131072);
        sqnorm_k<<<NROWS / 4, 256, 0, stream>>>(E, sq);
        dist_topk_k<<<NROWS / 4, 256, 131072, stream>>>(E, sq, knn);
    }
    overlap_k<<<NPAIR, 64, 0, stream>>>(knn, pairs, refso, partial);
    final_k<<<1, 256, 0, stream>>>(partial, out);
}